// Round 1
// baseline (438.380 us; speedup 1.0000x reference)
//
#include <hip/hip_runtime.h>
#include <cfloat>
#include <cmath>

#define B_ 64
#define N_ 8192
#define D_ 128
#define M_ 64
#define ROWS 256
#define KD 32
#define NKD (D_ / KD)       // 4
#define CHUNKS (N_ / ROWS)  // 32
#define ALPHA_ 0.1f
#define EPS_ 1e-10f

// Kernel 1: per (b, n-chunk) block: C = x_tile . pv^T fused with min over n.
// 256 threads; thread = (trow 0..31, tm8 0..7); 8 rows x 8 protos register tile.
__global__ __launch_bounds__(256, 2)
void protomin_kernel(const float* __restrict__ x, const float* __restrict__ pv,
                     float* __restrict__ wsv, int* __restrict__ wsa) {
    __shared__ union U {
        float ps[D_][M_];                       // pv transposed: ps[d][m], 32 KB
        struct R { float rv[M_][33]; int ra[M_][33]; } red;  // epilogue overlay
    } u;
    __shared__ float xs[KD][ROWS];              // x tile transposed (swizzled), 32 KB
    __shared__ float x2s[ROWS];
    __shared__ float p2s[M_];

    const int tid   = threadIdx.x;
    const int bc    = blockIdx.x;
    const int b     = bc / CHUNKS;
    const int chunk = bc % CHUNKS;
    const int rowbase = chunk * ROWS;

    const int tm8  = tid & 7;
    const int trow = tid >> 3;
    const int m0   = tm8 * 8;
    const int r0   = trow * 8;

    // ---- stage pv transposed: ps[d][m] ----
#pragma unroll
    for (int p = 0; p < 8; ++p) {
        int li = p * 1024 + tid * 4;
        int m  = li >> 7;       // /128
        int d4 = li & 127;
        float4 v = *reinterpret_cast<const float4*>(pv + m * D_ + d4);
        u.ps[d4 + 0][m] = v.x;
        u.ps[d4 + 1][m] = v.y;
        u.ps[d4 + 2][m] = v.z;
        u.ps[d4 + 3][m] = v.w;
    }
    __syncthreads();

    // ---- p2[m] = sum_d pv[m][d]^2 (once per block) ----
    if (tid < M_) {
        float s = 0.f;
#pragma unroll 8
        for (int d = 0; d < D_; ++d) { float v = u.ps[d][tid]; s = fmaf(v, v, s); }
        p2s[tid] = s;
    }

    float acc[8][8];
#pragma unroll
    for (int i = 0; i < 8; ++i)
#pragma unroll
        for (int j = 0; j < 8; ++j) acc[i][j] = 0.f;
    float x2r = 0.f;  // thread t accumulates x2 of row t

    const float* xbase = x + ((size_t)b * N_ + rowbase) * D_;

    for (int kd = 0; kd < NKD; ++kd) {
        __syncthreads();
        // ---- stage x chunk: xs[d][swz(r,d)] ; swizzle kills 8-way write conflict
#pragma unroll
        for (int p = 0; p < 8; ++p) {
            int li = p * 1024 + tid * 4;
            int r  = li >> 5;
            int dd = li & 31;
            float4 v = *reinterpret_cast<const float4*>(
                xbase + (size_t)r * D_ + kd * KD + dd);
            int rb = r >> 3, rj = r & 7;
            float vv[4] = {v.x, v.y, v.z, v.w};
#pragma unroll
            for (int i = 0; i < 4; ++i) {
                int d = dd + i;
                xs[d][(((rb ^ ((d >> 2) & 7)) << 3) | rj)] = vv[i];
            }
        }
        __syncthreads();

        // ---- x2 partial: thread t sums squares of row t over this d-chunk ----
        {
            int rb = tid >> 3, rj = tid & 7;
#pragma unroll 8
            for (int d = 0; d < KD; ++d) {
                float v = xs[d][(((rb ^ ((d >> 2) & 7)) << 3) | rj)];
                x2r = fmaf(v, v, x2r);
            }
        }

        // ---- main FMA loop: 8x8 register tile ----
        const int dbase = kd * KD;
#pragma unroll 4
        for (int d = 0; d < KD; ++d) {
            int sb = ((trow ^ ((d >> 2) & 7)) << 3);
            float4 xa = *reinterpret_cast<const float4*>(&xs[d][sb]);
            float4 xb = *reinterpret_cast<const float4*>(&xs[d][sb + 4]);
            float4 pa = *reinterpret_cast<const float4*>(&u.ps[dbase + d][m0]);
            float4 pb = *reinterpret_cast<const float4*>(&u.ps[dbase + d][m0 + 4]);
            float xv[8] = {xa.x, xa.y, xa.z, xa.w, xb.x, xb.y, xb.z, xb.w};
            float pw[8] = {pa.x, pa.y, pa.z, pa.w, pb.x, pb.y, pb.z, pb.w};
#pragma unroll
            for (int i = 0; i < 8; ++i)
#pragma unroll
                for (int j = 0; j < 8; ++j)
                    acc[i][j] = fmaf(xv[i], pw[j], acc[i][j]);
        }
    }

    __syncthreads();          // all ps/xs reads done
    x2s[tid] = x2r;
    __syncthreads();

    float4 xa2 = *reinterpret_cast<const float4*>(&x2s[r0]);
    float4 xb2 = *reinterpret_cast<const float4*>(&x2s[r0 + 4]);
    float x2v[8] = {xa2.x, xa2.y, xa2.z, xa2.w, xb2.x, xb2.y, xb2.z, xb2.w};
    float4 p2a = *reinterpret_cast<const float4*>(&p2s[m0]);
    float4 p2b = *reinterpret_cast<const float4*>(&p2s[m0 + 4]);
    float p2v[8] = {p2a.x, p2a.y, p2a.z, p2a.w, p2b.x, p2b.y, p2b.z, p2b.w};

    // per-thread min over its 8 rows (ascending n, strict < => first-min like jnp)
#pragma unroll
    for (int j = 0; j < 8; ++j) {
        float bv = FLT_MAX; int ba = 0;
        float p2j = p2v[j];
#pragma unroll
        for (int i = 0; i < 8; ++i) {
            float d2 = fmaf(-2.f, acc[i][j], x2v[i] + p2j);
            if (d2 < bv) { bv = d2; ba = rowbase + r0 + i; }
        }
        u.red.rv[m0 + j][trow] = bv;
        u.red.ra[m0 + j][trow] = ba;
    }
    __syncthreads();

    // cross-thread reduce per m (trow ascending = n ascending)
    if (tid < M_) {
        float bv = FLT_MAX; int ba = 0;
        for (int k = 0; k < 32; ++k) {
            float v = u.red.rv[tid][k];
            if (v < bv) { bv = v; ba = u.red.ra[tid][k]; }
        }
        wsv[(size_t)bc * M_ + tid] = bv;
        wsa[(size_t)bc * M_ + tid] = ba;
    }
}

// Kernel 2: reduce chunks, sqrt/exp, per-batch argmin over m.
__global__ void finalize_kernel(const float* __restrict__ wsv,
                                const int* __restrict__ wsa,
                                float* __restrict__ out) {
    const int b = blockIdx.x;
    const int m = threadIdx.x;
    float bv = FLT_MAX; int ba = 0;
    for (int c = 0; c < CHUNKS; ++c) {           // chunk order = n order
        size_t idx = ((size_t)b * CHUNKS + c) * M_ + m;
        float v = wsv[idx];
        if (v < bv) { bv = v; ba = wsa[idx]; }
    }
    float dist = sqrtf(fmaxf(bv, 0.f));
    out[b * M_ + m] = expf(EPS_ - ALPHA_ * dist);

    __shared__ float sv[M_];
    __shared__ int   sa[M_];
    sv[m] = dist; sa[m] = ba;
    __syncthreads();
    if (m == 0) {
        float best = FLT_MAX; int bp = 0;
        for (int k = 0; k < M_; ++k) {           // ascending m, strict <
            if (sv[k] < best) { best = sv[k]; bp = sa[k]; }
        }
        out[B_ * M_ + b] = (float)bp;            // min_pos as float
    }
}

extern "C" void kernel_launch(void* const* d_in, const int* in_sizes, int n_in,
                              void* d_out, int out_size, void* d_ws, size_t ws_size,
                              hipStream_t stream) {
    const float* x  = (const float*)d_in[0];
    const float* pv = (const float*)d_in[1];
    float* out = (float*)d_out;

    float* wsv = (float*)d_ws;
    int*   wsa = (int*)((char*)d_ws + (size_t)B_ * CHUNKS * M_ * sizeof(float));

    hipLaunchKernelGGL(protomin_kernel, dim3(B_ * CHUNKS), dim3(256), 0, stream,
                       x, pv, wsv, wsa);
    hipLaunchKernelGGL(finalize_kernel, dim3(B_), dim3(M_), 0, stream,
                       wsv, wsa, out);
}